// Round 14
// baseline (361.890 us; speedup 1.0000x reference)
//
#include <hip/hip_runtime.h>
#include <hip/hip_bf16.h>
#include <hip/hip_cooperative_groups.h>

typedef __attribute__((ext_vector_type(8))) short short8;
typedef __attribute__((ext_vector_type(4))) short short4v;
typedef __attribute__((ext_vector_type(4))) float f32x4;

#define B_ 16
#define T_ 1024
#define C_ 512
#define NH 8
#define HD 64

__device__ __forceinline__ short f2bf(float f) {
  union { float f; unsigned u; } v;
  v.f = f;
  unsigned r = v.u + 0x7fffu + ((v.u >> 16) & 1u);
  return (short)(r >> 16);
}

__device__ __forceinline__ short2 pack_bf2(float a, float b) {
  __hip_bfloat162 t = __float22bfloat162_rn(make_float2(a, b));
  short2 r;
  __builtin_memcpy(&r, &t, 4);
  return r;
}

// bare v_exp_f32: computes 2^x. The softmax scale folds log2(e) into Q
// at gemm_qkv, so scores arrive pre-multiplied — saves one v_mul per exp.
__device__ __forceinline__ float fexp2(float x) {
  float r;
  asm("v_exp_f32 %0, %1" : "=v"(r) : "v"(x));
  return r;
}

__device__ __forceinline__ void gload_lds16(const short* g, short* l) {
  __builtin_amdgcn_global_load_lds(
      (const __attribute__((address_space(1))) void*)g,
      (__attribute__((address_space(3))) void*)l, 16, 0, 0);
}

// ---------------- stage 1+2 fused: stats + weight transpose + normalize -----
// r14: cooperative kernel — x is read ONCE and held in registers across
// grid.sync() (was: stats read 64MB, then norm re-read 64MB). 1024 blocks x
// 256 threads = exactly 4 blocks/CU co-resident (launch_bounds(256,4) caps
// VGPR at 128; payload 8 x float4 = 32 VGPR; LDS 2KB). Each block owns an
// 8KB float slice of one sample (64 blocks/sample) + 1024 weight-transpose
// elements. Phase 1: reg-load + block reduce -> partials[blk]; transpose.
// grid.sync(). Phase 2: reduce own sample's 64 partials (r12 norm head),
// normalize registers, store xn. Saves ~64MB HBM read + one launch gap.
__global__ __launch_bounds__(256, 4) void statsnorm_kernel(
    const float* __restrict__ x, const float* __restrict__ gamma,
    const float* __restrict__ beta,
    const float* __restrict__ wq, const float* __restrict__ wk,
    const float* __restrict__ wv, const float* __restrict__ wo,
    short* __restrict__ wqkvT, short* __restrict__ woT,
    float2* __restrict__ partials, short* __restrict__ xn) {
  int tid = threadIdx.x;
  int blk = blockIdx.x;
  int b = blk >> 6;                       // 64 blocks per sample
  size_t base4 = (size_t)blk * 2048 + tid;  // float4 index
  const float4* x4 = (const float4*)x;
  float4 v[8];
  float s = 0.f, s2 = 0.f;
#pragma unroll
  for (int i = 0; i < 8; i++) {
    v[i] = x4[base4 + i * 256];
    s  += v[i].x + v[i].y + v[i].z + v[i].w;
    s2 += v[i].x * v[i].x + v[i].y * v[i].y + v[i].z * v[i].z + v[i].w * v[i].w;
  }
  __shared__ float ls[256], ls2[256];
  __shared__ float sm[2];
  ls[tid] = s; ls2[tid] = s2;
  __syncthreads();
  for (int o = 128; o > 0; o >>= 1) {
    if (tid < o) { ls[tid] += ls[tid + o]; ls2[tid] += ls2[tid + o]; }
    __syncthreads();
  }
  if (tid == 0) partials[blk] = make_float2(ls[0], ls2[0]);
  // weight transpose share: 4 elements/thread (1M elems over 1024 blocks)
#pragma unroll
  for (int k2 = 0; k2 < 4; k2++) {
    int o = blk * 1024 + k2 * 256 + tid;
    int sel = o >> 18;
    int oo = o & 262143;
    int kk = oo >> 9, n = oo & 511;
    const float* w = (sel == 0) ? wq : (sel == 1) ? wk : (sel == 2) ? wv : wo;
    float val = w[oo];
    if (sel < 3) wqkvT[((size_t)(sel * 512 + n)) * 512 + kk] = f2bf(val);
    else         woT[(size_t)n * 512 + kk] = f2bf(val);
  }

  cooperative_groups::this_grid().sync();

  if (tid < 64) {
    float2 p = partials[b * 64 + tid];
    float ss = p.x, ss2 = p.y;
#pragma unroll
    for (int off = 1; off < 64; off <<= 1) {
      ss  += __shfl_xor(ss,  off, 64);
      ss2 += __shfl_xor(ss2, off, 64);
    }
    if (tid == 0) {
      float mean = ss * (1.f / 524288.f);
      float var  = ss2 * (1.f / 524288.f) - mean * mean;
      sm[0] = mean;
      sm[1] = rsqrtf(var + 1e-5f);
    }
  }
  __syncthreads();
  float mean = sm[0], rstd = sm[1];
  int c = (int)((tid * 4) & 511);         // i*1024 === 0 (mod 512): c constant
  float g0 = gamma[c + 0], g1 = gamma[c + 1], g2 = gamma[c + 2], g3 = gamma[c + 3];
  float b0 = beta[c + 0],  b1 = beta[c + 1],  b2 = beta[c + 2],  b3 = beta[c + 3];
#pragma unroll
  for (int i = 0; i < 8; i++) {
    size_t i4 = base4 + i * 256;
    short4v o4;
    o4[0] = f2bf((v[i].x - mean) * rstd * g0 + b0);
    o4[1] = f2bf((v[i].y - mean) * rstd * g1 + b1);
    o4[2] = f2bf((v[i].z - mean) * rstd * g2 + b2);
    o4[3] = f2bf((v[i].w - mean) * rstd * g3 + b3);
    ((short4v*)xn)[i4] = o4;
  }
}

// ---------------- stage 4: fused QKV GEMM (BK=64 + XCD swizzle; r10-proven) --
__global__ __launch_bounds__(256) void gemm_qkv(const short* __restrict__ A,
                                                const short* __restrict__ Bt,
                                                const float* __restrict__ bq,
                                                const float* __restrict__ bk,
                                                const float* __restrict__ bv,
                                                short* __restrict__ C,
                                                short* __restrict__ vT) {
  __shared__ __align__(16) short As[2][128 * 32];
  __shared__ __align__(16) short Bs[2][128 * 32];
  int tid = threadIdx.x;
  int w = tid >> 6, lane = tid & 63;
  int quad = lane >> 4, l16 = lane & 15;
  int mw = (w >> 1) * 64, nw = (w & 1) * 64;
  int lin = blockIdx.y * 12 + blockIdx.x;   // linear dispatch id (x fastest)
  int my = (lin & 7) + ((lin / 96) << 3);   // M-tile 0..127 (XCD-chunked)
  int mx = (lin >> 3) % 12;                 // N-tile 0..11
  int seg = (mx * 128) >> 9;
  const float* bias = (seg == 0) ? bq : (seg == 1) ? bk : bv;
  float smul = (seg == 0) ? 0.18033688011112042f : 1.0f;
  const short* Atile = A + (size_t)(my * 128) * 512;
  const short* Btile = Bt + (size_t)(mx * 128) * 512;
  int srow = (w << 4) + (lane >> 2);
  int scol = (lane & 3) * 8;
  f32x4 acc[4][4] = {};
  for (int k0 = 0; k0 < 512; k0 += 64) {
    __syncthreads();
    gload_lds16(&Atile[(size_t)srow * 512 + k0 + scol],             &As[0][w * 512]);
    gload_lds16(&Atile[(size_t)(srow + 64) * 512 + k0 + scol],      &As[0][2048 + w * 512]);
    gload_lds16(&Atile[(size_t)srow * 512 + k0 + 32 + scol],        &As[1][w * 512]);
    gload_lds16(&Atile[(size_t)(srow + 64) * 512 + k0 + 32 + scol], &As[1][2048 + w * 512]);
    gload_lds16(&Btile[(size_t)srow * 512 + k0 + scol],             &Bs[0][w * 512]);
    gload_lds16(&Btile[(size_t)(srow + 64) * 512 + k0 + scol],      &Bs[0][2048 + w * 512]);
    gload_lds16(&Btile[(size_t)srow * 512 + k0 + 32 + scol],        &Bs[1][w * 512]);
    gload_lds16(&Btile[(size_t)(srow + 64) * 512 + k0 + 32 + scol], &Bs[1][2048 + w * 512]);
    __syncthreads();
    short8 af[2][4], bf[2][4];
#pragma unroll
    for (int s = 0; s < 2; s++)
#pragma unroll
      for (int i = 0; i < 4; i++) {
        af[s][i] = *(const short8*)(&As[s][(mw + i * 16 + l16) * 32 + quad * 8]);
        bf[s][i] = *(const short8*)(&Bs[s][(nw + i * 16 + l16) * 32 + quad * 8]);
      }
#pragma unroll
    for (int mi = 0; mi < 4; mi++)
#pragma unroll
      for (int ni = 0; ni < 4; ni++) {
        acc[mi][ni] = __builtin_amdgcn_mfma_f32_16x16x32_bf16(af[0][mi], bf[0][ni], acc[mi][ni], 0, 0, 0);
        acc[mi][ni] = __builtin_amdgcn_mfma_f32_16x16x32_bf16(af[1][mi], bf[1][ni], acc[mi][ni], 0, 0, 0);
      }
  }
  int m0 = my * 128 + mw;
  int n0 = mx * 128 + nw;
  if (seg < 2) {
#pragma unroll
    for (int mi = 0; mi < 4; mi++)
#pragma unroll
      for (int ni = 0; ni < 4; ni++) {
        int col = n0 + ni * 16 + l16;        // 0..1023 (Q|K)
        float bval = bias[col & 511];
#pragma unroll
        for (int r = 0; r < 4; r++) {
          int row = m0 + mi * 16 + quad * 4 + r;
          C[(size_t)row * 1024 + col] = f2bf((acc[mi][ni][r] + bval) * smul);
        }
      }
  } else {
    // V -> vT[(b*8+h)*64 + d][chunk*128 + slot]; slot = mi*32+quad*8+half*4+r
    int b = my >> 3;
    int chunk = my & 7;
    int half = mw >> 6;                      // 0 or 1
#pragma unroll
    for (int mi = 0; mi < 4; mi++)
#pragma unroll
      for (int ni = 0; ni < 4; ni++) {
        int c = (n0 - 1024) + ni * 16 + l16; // 0..511 v-col
        int h = c >> 6, d = c & 63;
        float bval = bias[c];
        short4v pk;
#pragma unroll
        for (int r = 0; r < 4; r++) pk[r] = f2bf(acc[mi][ni][r] + bval);
        short* dst = vT + ((size_t)((b * 8 + h) * 64 + d)) * 1024
                        + chunk * 128 + mi * 32 + quad * 8 + half * 4;
        *(short4v*)dst = pk;
      }
  }
}

// ---------------- stage 6: GEMM + bias + residual (fp32 out; r10-proven) ----
__global__ __launch_bounds__(256) void gemm_out(const short* __restrict__ A,
                                                const short* __restrict__ Bt,
                                                const float* __restrict__ bias,
                                                const float* __restrict__ xres,
                                                float* __restrict__ out) {
  __shared__ __align__(16) short As[2][128 * 32];
  __shared__ __align__(16) short Bs[2][128 * 32];
  int tid = threadIdx.x;
  int w = tid >> 6, lane = tid & 63;
  int quad = lane >> 4, l16 = lane & 15;
  int mw = (w >> 1) * 64, nw = (w & 1) * 64;
  int lin = blockIdx.y * 4 + blockIdx.x;    // linear dispatch id (x fastest)
  int my = (lin & 7) + ((lin / 32) << 3);   // M-tile 0..127 (XCD-chunked)
  int mx = (lin >> 3) & 3;                  // N-tile 0..3
  const short* Atile = A + (size_t)(my * 128) * 512;
  const short* Btile = Bt + (size_t)(mx * 128) * 512;
  int srow = (w << 4) + (lane >> 2);
  int scol = (lane & 3) * 8;
  f32x4 acc[4][4] = {};
  for (int k0 = 0; k0 < 512; k0 += 64) {
    __syncthreads();
    gload_lds16(&Atile[(size_t)srow * 512 + k0 + scol],             &As[0][w * 512]);
    gload_lds16(&Atile[(size_t)(srow + 64) * 512 + k0 + scol],      &As[0][2048 + w * 512]);
    gload_lds16(&Atile[(size_t)srow * 512 + k0 + 32 + scol],        &As[1][w * 512]);
    gload_lds16(&Atile[(size_t)(srow + 64) * 512 + k0 + 32 + scol], &As[1][2048 + w * 512]);
    gload_lds16(&Btile[(size_t)srow * 512 + k0 + scol],             &Bs[0][w * 512]);
    gload_lds16(&Btile[(size_t)(srow + 64) * 512 + k0 + scol],      &Bs[0][2048 + w * 512]);
    gload_lds16(&Btile[(size_t)srow * 512 + k0 + 32 + scol],        &Bs[1][w * 512]);
    gload_lds16(&Btile[(size_t)(srow + 64) * 512 + k0 + 32 + scol], &Bs[1][2048 + w * 512]);
    __syncthreads();
    short8 af[2][4], bf[2][4];
#pragma unroll
    for (int s = 0; s < 2; s++)
#pragma unroll
      for (int i = 0; i < 4; i++) {
        af[s][i] = *(const short8*)(&As[s][(mw + i * 16 + l16) * 32 + quad * 8]);
        bf[s][i] = *(const short8*)(&Bs[s][(nw + i * 16 + l16) * 32 + quad * 8]);
      }
#pragma unroll
    for (int mi = 0; mi < 4; mi++)
#pragma unroll
      for (int ni = 0; ni < 4; ni++) {
        acc[mi][ni] = __builtin_amdgcn_mfma_f32_16x16x32_bf16(af[0][mi], bf[0][ni], acc[mi][ni], 0, 0, 0);
        acc[mi][ni] = __builtin_amdgcn_mfma_f32_16x16x32_bf16(af[1][mi], bf[1][ni], acc[mi][ni], 0, 0, 0);
      }
  }
  int m0 = my * 128 + mw;
  int n0 = mx * 128 + nw;
#pragma unroll
  for (int mi = 0; mi < 4; mi++)
#pragma unroll
    for (int ni = 0; ni < 4; ni++) {
      int col = n0 + ni * 16 + l16;
      float bval = bias[col];
#pragma unroll
      for (int r = 0; r < 4; r++) {
        int row = m0 + mi * 16 + quad * 4 + r;
        out[(size_t)row * 512 + col] = acc[mi][ni][r] + bval + xres[(size_t)row * 512 + col];
      }
    }
}

// ---------------- stage 5: attention — r13 (r10 dataflow + LDS 32768) -------
// FROZEN. r13 verdict: occupancy lever null (dur flat at 69.5, Occ ~20%);
// trim kept (total best, LDS 32768). attn is parked at ~69us — schedule x2,
// wave-merge x2, occupancy x1 all null/failed. (8-wave merged-qt ABANDONED:
// r4 NaN, r11 absmax 0.18.)
__global__ __launch_bounds__(256) void attn_kernel(const short* __restrict__ Q,
                                                   const short* __restrict__ Kmat,
                                                   const short* __restrict__ vTg,
                                                   short* __restrict__ O) {
  int tid = threadIdx.x;
  int w = tid >> 6, lane = tid & 63;
  int quad = lane >> 4, l16 = lane & 15;
  int lin = blockIdx.y * 128 + blockIdx.x;   // linear dispatch id (x fastest)
  int bh = (lin & 7) * 16 + (lin >> 7);      // XCD-chunked: xcd owns 16 bh
  int qt = (lin >> 3) & 15;                  // 16 same-bh blocks consecutive
  int b = bh >> 3, h = bh & 7;
  size_t base  = ((size_t)b * T_) * 1024 + (size_t)h * 64;
  size_t vbase = ((size_t)bh * 64) * 1024;
  size_t obase = ((size_t)b * T_) * 512 + (size_t)h * 64;
  int qrow0 = qt * 64;

  __shared__ __align__(16) char smem[32768];
  short* KTb[2];
  KTb[0] = (short*)smem;                    // K dbuf half 0: 128 keys x 64d, swizzled
  KTb[1] = (short*)(smem + 16384);          // K dbuf half 1
  float* Lbuf = (float*)smem;               // epilogue union [q][68]; cols 64-67 = denom pad

  // Q as B-frags: B[k=d=quad*8+j][n=q=l16], 4 q-tiles x 2 d-halves
  short8 qf0[4], qf1[4];
#pragma unroll
  for (int g = 0; g < 4; g++) {
    const short* qp = Q + base + (size_t)(qrow0 + g * 16 + l16) * 1024 + quad * 8;
    qf0[g] = *(const short8*)qp;
    qf1[g] = *(const short8*)(qp + 32);
  }

  // K staging descriptors: lane's 16B block index bk = w*256 + n*64 + lane,
  // bank swizzle applied on the GLOBAL address side (LDS dst stays linear).
  const short* ksrc[4];
#pragma unroll
  for (int n = 0; n < 4; n++) {
    int bk = w * 256 + n * 64 + lane;
    int key = bk >> 3, jc = bk & 7;
    int dcol = jc ^ (key & 7);
    ksrc[n] = Kmat + base + (size_t)key * 1024 + dcol * 8;
  }

  // V fragment base: d-row = l16 (+f*16), key-slot = w*4+quad (vT layout)
  const short* vp0 = vTg + vbase + (size_t)l16 * 1024 + (w * 4 + quad) * 8;

  // K fragment LDS offsets (shorts), loop-invariant
  int l7 = l16 & 7;
  int kA0 = ((w * 16 + l16) * 8 + (quad ^ l7)) * 8;
  int kA1 = ((w * 16 + l16) * 8 + ((quad + 4) ^ l7)) * 8;
  int kB0 = kA0 + 4096;   // key + 64
  int kB1 = kA1 + 4096;

  f32x4 oacc[4][4] = {};   // O^T[d-tile f][q-tile g]
  float lsum[4] = {0.f, 0.f, 0.f, 0.f};

  // prologue: stage tile 0 into buffer 0
#pragma unroll
  for (int n = 0; n < 4; n++)
    gload_lds16(ksrc[n], KTb[0] + (w * 256 + n * 64) * 8);

#pragma unroll
  for (int t = 0; t < 8; t++) {
    short* KTc = KTb[t & 1];
    short* KTn = KTb[(t + 1) & 1];
    __syncthreads();   // drains vmcnt: K(t) staged; KTn's last readers done
    // V fragments for tile t: global->reg, issued first
    short8 vfr[4];
#pragma unroll
    for (int f = 0; f < 4; f++)
      vfr[f] = *(const short8*)(vp0 + (size_t)f * 16384 + t * 128);
    // stage K(t+1) into the other buffer — in flight across this whole phase
    if (t < 7) {
#pragma unroll
      for (int n = 0; n < 4; n++)
        gload_lds16(ksrc[n] + (size_t)(t + 1) * 131072, KTn + (w * 256 + n * 64) * 8);
    }
    // K fragments for tile t from LDS
    short8 ka0 = *(const short8*)(KTc + kA0);
    short8 ka1 = *(const short8*)(KTc + kA1);
    short8 kb0 = *(const short8*)(KTc + kB0);
    short8 kb1 = *(const short8*)(KTc + kB1);

#pragma unroll
    for (int g = 0; g < 4; g++) {
      f32x4 za = {}, zb = {};
      __builtin_amdgcn_s_setprio(1);
      za = __builtin_amdgcn_mfma_f32_16x16x32_bf16(ka0, qf0[g], za, 0, 0, 0);
      za = __builtin_amdgcn_mfma_f32_16x16x32_bf16(ka1, qf1[g], za, 0, 0, 0);
      zb = __builtin_amdgcn_mfma_f32_16x16x32_bf16(kb0, qf0[g], zb, 0, 0, 0);
      zb = __builtin_amdgcn_mfma_f32_16x16x32_bf16(kb1, qf1[g], zb, 0, 0, 0);
      __builtin_amdgcn_s_setprio(0);
      float pa0 = fexp2(za[0]), pa1 = fexp2(za[1]);
      float pa2 = fexp2(za[2]), pa3 = fexp2(za[3]);
      float pb0 = fexp2(zb[0]), pb1 = fexp2(zb[1]);
      float pb2 = fexp2(zb[2]), pb3 = fexp2(zb[3]);
      lsum[g] += (pa0 + pa1) + (pa2 + pa3) + ((pb0 + pb1) + (pb2 + pb3));
      short2 a01 = pack_bf2(pa0, pa1), a23 = pack_bf2(pa2, pa3);
      short2 b01 = pack_bf2(pb0, pb1), b23 = pack_bf2(pb2, pb3);
      short8 pf;
      pf[0] = a01.x; pf[1] = a01.y; pf[2] = a23.x; pf[3] = a23.y;
      pf[4] = b01.x; pf[5] = b01.y; pf[6] = b23.x; pf[7] = b23.y;
      __builtin_amdgcn_s_setprio(1);
#pragma unroll
      for (int f = 0; f < 4; f++)
        oacc[f][g] = __builtin_amdgcn_mfma_f32_16x16x32_bf16(vfr[f], pf, oacc[f][g], 0, 0, 0);
      __builtin_amdgcn_s_setprio(0);
    }
  }

  // per-lane lsum covers this wave's keys for query g*16+l16; sum over quads
#pragma unroll
  for (int g = 0; g < 4; g++) {
    lsum[g] += __shfl_xor(lsum[g], 16, 64);
    lsum[g] += __shfl_xor(lsum[g], 32, 64);
  }
  // all K-LDS reads are done; smem can be repurposed as Lbuf from here
  __syncthreads();
  // denominators into the row pad: Lbuf[q][64+w] (cols 64..67, untouched by
  // the O^T accumulation which writes cols 0..63 only)
  if (quad == 0) {
#pragma unroll
    for (int g = 0; g < 4; g++)
      Lbuf[(g * 16 + l16) * 68 + 64 + w] = lsum[g];
  }
  // sequential cross-wave accumulation of O^T into Lbuf (transposed to [q][d])
  for (int ww = 0; ww < 4; ww++) {
    __syncthreads();
    if (w == ww) {
#pragma unroll
      for (int g = 0; g < 4; g++)
#pragma unroll
        for (int f = 0; f < 4; f++) {
          float* p = &Lbuf[(g * 16 + l16) * 68 + f * 16 + quad * 4];
          if (ww == 0) *(f32x4*)p = oacc[f][g];
          else         *(f32x4*)p = *(f32x4*)p + oacc[f][g];
        }
    }
  }
  __syncthreads();

  // coalesced writeout: thread -> (q = tid/4, 16-wide d segment)
  int q = tid >> 2, seg = tid & 3;
  float4 dnv = *(const float4*)(&Lbuf[q * 68 + 64]);
  float dn = (dnv.x + dnv.y) + (dnv.z + dnv.w);
  float rinv = __frcp_rn(dn);
  const float* row = &Lbuf[q * 68 + seg * 16];
  short8 o0, o1;
#pragma unroll
  for (int i = 0; i < 8; i++) o0[i] = f2bf(row[i] * rinv);
#pragma unroll
  for (int i = 0; i < 8; i++) o1[i] = f2bf(row[8 + i] * rinv);
  short* op = O + obase + (size_t)(qrow0 + q) * 512 + seg * 16;
  *(short8*)op = o0;
  *(short8*)(op + 8) = o1;
}

extern "C" void kernel_launch(void* const* d_in, const int* in_sizes, int n_in,
                              void* d_out, int out_size, void* d_ws, size_t ws_size,
                              hipStream_t stream) {
  const float* x     = (const float*)d_in[0];
  const float* gamma = (const float*)d_in[1];
  const float* beta  = (const float*)d_in[2];
  const float* wq    = (const float*)d_in[3];
  const float* bq    = (const float*)d_in[4];
  const float* wk    = (const float*)d_in[5];
  const float* bk    = (const float*)d_in[6];
  const float* wv    = (const float*)d_in[7];
  const float* bv    = (const float*)d_in[8];
  const float* wo    = (const float*)d_in[9];
  const float* bo    = (const float*)d_in[10];
  float* out = (float*)d_out;

  char* ws = (char*)d_ws;
  const size_t XN_ELEMS = (size_t)B_ * T_ * C_;
  size_t off = 0;
  off += 256;                                              // (reserved)
  float2* partials = (float2*)(ws + off); off += 1024 * sizeof(float2);
  short* xn    = (short*)(ws + off); off += XN_ELEMS * 2;
  short* wqkvT = (short*)(ws + off); off += (size_t)1536 * 512 * 2;
  short* woT   = (short*)(ws + off); off += (size_t)512 * 512 * 2;
  short* qkv   = (short*)(ws + off); off += (size_t)B_ * T_ * 1024 * 2;  // Q|K compact
  short* vTb   = (short*)(ws + off); off += XN_ELEMS * 2;
  short* ao    = (short*)(ws + off); off += XN_ELEMS * 2;

  // fused stats+transpose+norm: cooperative (grid.sync), x read once
  void* args[] = {(void*)&x, (void*)&gamma, (void*)&beta,
                  (void*)&wq, (void*)&wk, (void*)&wv, (void*)&wo,
                  (void*)&wqkvT, (void*)&woT, (void*)&partials, (void*)&xn};
  hipLaunchCooperativeKernel((void*)statsnorm_kernel, dim3(1024), dim3(256),
                             args, 0, stream);

  gemm_qkv<<<dim3(12, 128), 256, 0, stream>>>(xn, wqkvT, bq, bk, bv, qkv, vTb);

  attn_kernel<<<dim3(128, 16), 256, 0, stream>>>(qkv, qkv + 512, vTb, ao);

  gemm_out<<<dim3(4, 128), 256, 0, stream>>>(ao, woT, bo, x, out);
}